// Round 3
// baseline (1140.846 us; speedup 1.0000x reference)
//
#include <hip/hip_runtime.h>

#define N_NODES 100000
#define N_EDGES 1600000
#define M_PAD   100096   // 782 * 128
#define BCAP    64       // bucket capacity per node (Poisson(16): P(>=64) ~ 1e-20)
#define E_SPLIT 1000000  // edges handled inside GEMM1's window; rest inside GEMM2's
#define X_REAL 51200000L          // N_NODES*512
#define X_PAD  ((long)M_PAD*512)  // 51249152, divisible by 2048

typedef __bf16 bf16x8 __attribute__((ext_vector_type(8)));
typedef float  f32x4  __attribute__((ext_vector_type(4)));
typedef unsigned short u16x8 __attribute__((ext_vector_type(8)));

__device__ __forceinline__ unsigned short f2bf(float f) {
  union { float f; unsigned u; } x; x.f = f;
  unsigned r = (x.u + 0x7FFFu + ((x.u >> 16) & 1u)) >> 16;
  return (unsigned short)r;
}

__device__ __forceinline__ float bf2f(unsigned short h) {
  union { unsigned u; float f; } x; x.u = ((unsigned)h) << 16;
  return x.f;
}

__device__ __forceinline__ void async_copy16(const void* g, void* l) {
  __builtin_amdgcn_global_load_lds((__attribute__((address_space(1))) void*)g,
                                   (__attribute__((address_space(3))) void*)l,
                                   16, 0, 0);
}

// ---------------- prep kernels ----------------

__global__ void cvt_x_kernel(const float* __restrict__ x, unsigned short* __restrict__ xb) {
  long e = ((long)blockIdx.x * 256 + threadIdx.x) * 8;   // grid sized exactly: X_PAD/8/256 blocks
  u16x8 o;
  if (e < X_REAL) {
    float4 f0 = *(const float4*)(x + e);
    float4 f1 = *(const float4*)(x + e + 4);
    o[0] = f2bf(f0.x); o[1] = f2bf(f0.y); o[2] = f2bf(f0.z); o[3] = f2bf(f0.w);
    o[4] = f2bf(f1.x); o[5] = f2bf(f1.y); o[6] = f2bf(f1.z); o[7] = f2bf(f1.w);
  } else {
    o = (u16x8)0;
  }
  *(u16x8*)(xb + e) = o;
}

// W [K][N] fp32 -> Wt [Npad][K] bf16 (rows >= N zero-filled)
__global__ void cvt_wt_kernel(const float* __restrict__ W, unsigned short* __restrict__ Wt,
                              int K, int N, int Npad) {
  int idx = blockIdx.x * 256 + threadIdx.x;
  if (idx >= Npad * K) return;
  int n = idx / K, k = idx % K;
  Wt[idx] = (n < N) ? f2bf(W[(long)k * N + n]) : (unsigned short)0;
}

// W [64][N] fp32 -> Wt [64][128] bf16 with K duplicated: Wt[n][k] = W[k&63][n]
// (B operand for hi/lo-decomposed A: sum_k (hi_k + lo_k) * W)
__global__ void cvt_wt_dup_kernel(const float* __restrict__ W, unsigned short* __restrict__ Wt,
                                  int N) {
  int idx = blockIdx.x * 256 + threadIdx.x;
  if (idx >= 64 * 128) return;
  int n = idx >> 7, k = idx & 127;
  Wt[idx] = (n < N) ? f2bf(W[(long)(k & 63) * N + n]) : (unsigned short)0;
}

__global__ void norms_kernel(const int* __restrict__ hist,
                             float* __restrict__ nsrc, float* __restrict__ ndst) {
  int i = blockIdx.x * 256 + threadIdx.x;
  if (i >= M_PAD) return;
  if (i < N_NODES) {
    nsrc[i] = rsqrtf(fmaxf((float)hist[N_NODES + i], 1.f));  // deg_out
    ndst[i] = rsqrtf(fmaxf((float)hist[i], 1.f));            // deg_in
  } else {
    nsrc[i] = 1.f;
  }
}

// ---------------- GEMM: C = A(bf16,[M_PAD][K]) x Bt(bf16,[Nfull][K])^T ----------------
// EPI 0: bf16( relu(acc + bias[col]) )
// EPI 1: bf16( relu(acc + bias[col]) * rowscale[row] )
// EDGES: blocks with blockIdx.x == gridDim.x-1 process the edge range [eBeg,eEnd):
//        adjacency buckets + degree histograms (atomic-latency-bound role overlapped
//        with the MFMA-bound GEMM; interleaved in dispatch order -> co-resident).
template <int BM, int BN, int BK, int EPI, bool EDGES>
__launch_bounds__(256)
__global__ void gemm_bt(const unsigned short* __restrict__ A,
                        const unsigned short* __restrict__ Bt,
                        const float* __restrict__ bias,
                        const float* __restrict__ rowscale,
                        void* __restrict__ C, int K, int Nfull,
                        const int* __restrict__ esrc, const int* __restrict__ edst,
                        int eBeg, int eEnd,
                        int* __restrict__ hist, int* __restrict__ bucket) {
  if constexpr (EDGES) {
    if (blockIdx.x == gridDim.x - 1) {
      const int stride = gridDim.y * 256;
      for (int e = eBeg + blockIdx.y * 256 + threadIdx.x; e < eEnd; e += stride) {
        int s = esrc[e], d = edst[e];
        atomicAdd(&hist[N_NODES + s], 1);
        int p = atomicAdd(&hist[d], 1);
        if (p < BCAP) bucket[(size_t)d * BCAP + p] = s;
      }
      return;
    }
  }
  constexpr int WM = BM / 2, WN = BN / 2;
  constexpr int MI = WM / 16, NI = WN / 16;
  __shared__ __align__(16) unsigned short As[BM * BK];
  __shared__ __align__(16) unsigned short Bs[BN * BK];
  const int tid = threadIdx.x;
  const int wave = tid >> 6, lane = tid & 63;
  const int wm0 = (wave >> 1) * WM, wn0 = (wave & 1) * WN;
  const long rowBase = (long)blockIdx.y * BM;
  const int colBase = blockIdx.x * BN;
  const unsigned short* Ab = A + rowBase * K;
  const unsigned short* Bb = Bt + (long)colBase * K;
  f32x4 acc[MI][NI] = {};
  constexpr int ACH = BM * BK / 8;  // 16B chunks
  constexpr int BCH = BN * BK / 8;
  for (int k0 = 0; k0 < K; k0 += BK) {
#pragma unroll
    for (int c = tid; c < ACH; c += 256) {
      int r = (c * 8) / BK, cc = (c * 8) % BK;
      async_copy16(Ab + (long)r * K + k0 + cc, &As[c * 8]);
    }
#pragma unroll
    for (int c = tid; c < BCH; c += 256) {
      int r = (c * 8) / BK, cc = (c * 8) % BK;
      async_copy16(Bb + (long)r * K + k0 + cc, &Bs[c * 8]);
    }
    __syncthreads();
#pragma unroll
    for (int kk = 0; kk < BK; kk += 32) {
      bf16x8 af[MI], bfr[NI];
#pragma unroll
      for (int mi = 0; mi < MI; ++mi)
        af[mi] = *(const bf16x8*)&As[(wm0 + mi * 16 + (lane & 15)) * BK + kk + (lane >> 4) * 8];
#pragma unroll
      for (int ni = 0; ni < NI; ++ni)
        bfr[ni] = *(const bf16x8*)&Bs[(wn0 + ni * 16 + (lane & 15)) * BK + kk + (lane >> 4) * 8];
#pragma unroll
      for (int mi = 0; mi < MI; ++mi)
#pragma unroll
        for (int ni = 0; ni < NI; ++ni)
          acc[mi][ni] = __builtin_amdgcn_mfma_f32_16x16x32_bf16(af[mi], bfr[ni], acc[mi][ni], 0, 0, 0);
    }
    __syncthreads();
  }
  const int q = lane >> 4, c15 = lane & 15;
#pragma unroll
  for (int mi = 0; mi < MI; ++mi) {
#pragma unroll
    for (int ni = 0; ni < NI; ++ni) {
#pragma unroll
      for (int r = 0; r < 4; ++r) {
        long row = rowBase + wm0 + mi * 16 + q * 4 + r;
        int col = colBase + wn0 + ni * 16 + c15;
        float v = acc[mi][ni][r];
        if (EPI == 0) {
          v = fmaxf(v + bias[col], 0.f);
          ((unsigned short*)C)[row * Nfull + col] = f2bf(v);
        } else {  // EPI == 1
          v = fmaxf(v + bias[col], 0.f) * rowscale[row];
          ((unsigned short*)C)[row * Nfull + col] = f2bf(v);
        }
      }
    }
  }
}

// ---------------- fused GCN layer: aggregate (bf16 gather) + GEMM in one kernel ----
// Per block: 128 nodes. Phase 1: za[node][:] = ndst[node] * sum_{s in bucket} u[s][:]
// (f32 accumulate) written into LDS as a hi/lo bf16 pair (K=128 columns).
// Phase 2: MFMA against duplicated-W tile Bs[64][128]: acc = za_hi@W + za_lo@W ~ f32.
// FINAL 0: uout[row][col] = bf16( relu(acc + bias) * nsrc[row] )   (next layer input)
// FINAL 1: dout[row][c]   = relu(acc + bias)  for row<N_NODES, c<40
template <int FINAL>
__launch_bounds__(256)
__global__ void gcn_layer(const unsigned short* __restrict__ u,
                          const unsigned short* __restrict__ Wt,   // [64][128] dup-K bf16
                          const int* __restrict__ bucket, const int* __restrict__ cnt,
                          const float* __restrict__ ndst, const float* __restrict__ nsrc,
                          const float* __restrict__ bias,
                          unsigned short* __restrict__ uout, float* __restrict__ dout) {
  __shared__ __align__(16) unsigned short As[128 * 128];  // za tile: [row][hi0..63|lo0..63]
  __shared__ __align__(16) unsigned short Bs[64 * 128];
  const int tid = threadIdx.x;
  const int wave = tid >> 6, lane = tid & 63;
  const int nodeBase = blockIdx.x * 128;

  // stage W tile while aggregating (drained by the __syncthreads below)
#pragma unroll
  for (int c = tid; c < 64 * 128 / 8; c += 256)
    async_copy16(Wt + c * 8, &Bs[c * 8]);

  // ---- phase 1: aggregation. wave handles 32 consecutive local rows.
  // 8-way neighbor ILP: lane = r8*8 + colgrp; each lane covers 8 bf16 cols (16 B).
  const int r8 = lane >> 3;          // 0..7 neighbor slot
  const int c8 = (lane & 7) * 8;     // bf16 column start
  for (int j = 0; j < 32; ++j) {
    const int row_l = wave * 32 + j;
    const int node = nodeBase + row_l;
    float a0 = 0.f, a1 = 0.f, a2 = 0.f, a3 = 0.f, a4 = 0.f, a5 = 0.f, a6 = 0.f, a7 = 0.f;
    int n = 0;
    if (node < N_NODES) n = min(cnt[node], BCAP);
    const int* bk = bucket + (size_t)node * BCAP;
#pragma unroll 2
    for (int i = r8; i < n; i += 8) {
      int s = bk[i];
      u16x8 v = *(const u16x8*)(u + (size_t)s * 64 + c8);
      a0 += bf2f(v[0]); a1 += bf2f(v[1]); a2 += bf2f(v[2]); a3 += bf2f(v[3]);
      a4 += bf2f(v[4]); a5 += bf2f(v[5]); a6 += bf2f(v[6]); a7 += bf2f(v[7]);
    }
#pragma unroll
    for (int m = 8; m <= 32; m <<= 1) {
      a0 += __shfl_xor(a0, m); a1 += __shfl_xor(a1, m);
      a2 += __shfl_xor(a2, m); a3 += __shfl_xor(a3, m);
      a4 += __shfl_xor(a4, m); a5 += __shfl_xor(a5, m);
      a6 += __shfl_xor(a6, m); a7 += __shfl_xor(a7, m);
    }
    if (r8 == 0) {
      float nd = (node < N_NODES) ? ndst[node] : 0.f;
      float vv[8] = {nd * a0, nd * a1, nd * a2, nd * a3, nd * a4, nd * a5, nd * a6, nd * a7};
      u16x8 H, L;
#pragma unroll
      for (int t = 0; t < 8; ++t) {
        unsigned short h = f2bf(vv[t]);
        H[t] = h;
        L[t] = f2bf(vv[t] - bf2f(h));
      }
      *(u16x8*)&As[row_l * 128 + c8] = H;
      *(u16x8*)&As[row_l * 128 + 64 + c8] = L;
    }
  }
  __syncthreads();  // za tile + W tile both resident

  // ---- phase 2: GEMM. 4 waves in 2x2; per-wave 64x32 output; K=128.
  const int wm0 = (wave >> 1) * 64, wn0 = (wave & 1) * 32;
  f32x4 acc[4][2] = {};
#pragma unroll
  for (int kk = 0; kk < 128; kk += 32) {
    bf16x8 af[4], bfr[2];
#pragma unroll
    for (int mi = 0; mi < 4; ++mi)
      af[mi] = *(const bf16x8*)&As[(wm0 + mi * 16 + (lane & 15)) * 128 + kk + (lane >> 4) * 8];
#pragma unroll
    for (int ni = 0; ni < 2; ++ni)
      bfr[ni] = *(const bf16x8*)&Bs[(wn0 + ni * 16 + (lane & 15)) * 128 + kk + (lane >> 4) * 8];
#pragma unroll
    for (int mi = 0; mi < 4; ++mi)
#pragma unroll
      for (int ni = 0; ni < 2; ++ni)
        acc[mi][ni] = __builtin_amdgcn_mfma_f32_16x16x32_bf16(af[mi], bfr[ni], acc[mi][ni], 0, 0, 0);
  }

  const int q = lane >> 4, c15 = lane & 15;
#pragma unroll
  for (int mi = 0; mi < 4; ++mi) {
#pragma unroll
    for (int ni = 0; ni < 2; ++ni) {
#pragma unroll
      for (int r = 0; r < 4; ++r) {
        int row = nodeBase + wm0 + mi * 16 + q * 4 + r;   // < M_PAD
        int col = wn0 + ni * 16 + c15;                    // < 64
        float bv = (FINAL && col >= 40) ? 0.f : bias[col];
        float v = fmaxf(acc[mi][ni][r] + bv, 0.f);
        if constexpr (FINAL) {
          if (row < N_NODES && col < 40)
            dout[(size_t)row * 40 + col] = v;
        } else {
          uout[(size_t)row * 64 + col] = f2bf(v * nsrc[row]);
        }
      }
    }
  }
}

// ---------------- launch ----------------

extern "C" void kernel_launch(void* const* d_in, const int* in_sizes, int n_in,
                              void* d_out, int out_size, void* d_ws, size_t ws_size,
                              hipStream_t stream) {
  (void)in_sizes; (void)n_in; (void)out_size; (void)ws_size;
  const float* x   = (const float*)d_in[0];
  const int* esrc  = (const int*)d_in[1];
  const int* edst  = (const int*)d_in[2];
  const float* W1  = (const float*)d_in[3];  const float* b1  = (const float*)d_in[4];
  const float* W2  = (const float*)d_in[5];  const float* b2  = (const float*)d_in[6];
  const float* W3  = (const float*)d_in[7];  const float* b3  = (const float*)d_in[8];
  const float* Wg1 = (const float*)d_in[9];  const float* bg1 = (const float*)d_in[10];
  const float* Wg2 = (const float*)d_in[11]; const float* bg2 = (const float*)d_in[12];
  const float* Wg3 = (const float*)d_in[13]; const float* bg3 = (const float*)d_in[14];
  const float* Wg4 = (const float*)d_in[15]; const float* bg4 = (const float*)d_in[16];
  float* out = (float*)d_out;

  char* ws = (char*)d_ws;
  size_t off = 0;
  auto alloc = [&](size_t bytes) -> void* {
    void* p = ws + off;
    off += (bytes + 255) & ~(size_t)255;
    return p;
  };

  unsigned short* xb = (unsigned short*)alloc((size_t)M_PAD * 512 * 2);  // region0 (reused)
  unsigned short* h1 = (unsigned short*)alloc((size_t)M_PAD * 512 * 2);
  int*   bucket  = (int*)alloc((size_t)N_NODES * BCAP * 4);
  int*   hist    = (int*)alloc((size_t)2 * N_NODES * 4);
  float* nsrc    = (float*)alloc((size_t)M_PAD * 4);
  float* ndst    = (float*)alloc((size_t)N_NODES * 4);
  unsigned short* W1t  = (unsigned short*)alloc(512 * 512 * 2);
  unsigned short* W2t  = (unsigned short*)alloc(256 * 512 * 2);
  unsigned short* W3t  = (unsigned short*)alloc(64 * 256 * 2);
  unsigned short* Wg1t = (unsigned short*)alloc(64 * 128 * 2);   // dup-K layout
  unsigned short* Wg2t = (unsigned short*)alloc(64 * 128 * 2);
  unsigned short* Wg3t = (unsigned short*)alloc(64 * 128 * 2);
  unsigned short* Wg4t = (unsigned short*)alloc(64 * 128 * 2);

  // region0 reuse (xb dead after layer-1 GEMM); h2 + U0 + U1 = 76.9 MB <= 102.4 MB:
  unsigned short* h2 = xb;                                                      // M_PAD*256 bf16
  unsigned short* U0 = (unsigned short*)((char*)xb + (size_t)M_PAD * 256 * 2);  // M_PAD*64 bf16
  unsigned short* U1 = (unsigned short*)((char*)U0 + (size_t)M_PAD * 64 * 2);   // M_PAD*64 bf16

  // 1) zero both histograms — exact size
  hipMemsetAsync(hist, 0, (size_t)2 * N_NODES * 4, stream);

  // 2) x -> bf16 padded
  cvt_x_kernel<<<(int)(X_PAD / 8 / 256), 256, 0, stream>>>(x, xb);

  // 3) weights -> bf16 transposed [Npad][K]; GCN weights in dup-K [64][128]
  cvt_wt_kernel<<<(512 * 512 + 255) / 256, 256, 0, stream>>>(W1, W1t, 512, 512, 512);
  cvt_wt_kernel<<<(256 * 512 + 255) / 256, 256, 0, stream>>>(W2, W2t, 512, 256, 256);
  cvt_wt_kernel<<<(64 * 256 + 255) / 256, 256, 0, stream>>>(W3, W3t, 256, 64, 64);
  cvt_wt_dup_kernel<<<(64 * 128 + 255) / 256, 256, 0, stream>>>(Wg1, Wg1t, 64);
  cvt_wt_dup_kernel<<<(64 * 128 + 255) / 256, 256, 0, stream>>>(Wg2, Wg2t, 64);
  cvt_wt_dup_kernel<<<(64 * 128 + 255) / 256, 256, 0, stream>>>(Wg3, Wg3t, 64);
  cvt_wt_dup_kernel<<<(64 * 128 + 255) / 256, 256, 0, stream>>>(Wg4, Wg4t, 40);  // pad 40->64

  const int GY = M_PAD / 128;  // 782

  // 4) GEMM1 fused with edge slice [0, E_SPLIT): x=0..3 GEMM cols, x=4 edge role.
  gemm_bt<128, 128, 64, 0, true><<<dim3(5, GY), 256, 0, stream>>>(
      xb, W1t, b1, nullptr, h1, 512, 512, esrc, edst, 0, E_SPLIT, hist, bucket);

  // 5) GEMM2 fused with edge slice [E_SPLIT, N_EDGES): x=0..1 GEMM cols, x=2 edge role.
  gemm_bt<128, 128, 64, 0, true><<<dim3(3, GY), 256, 0, stream>>>(
      h1, W2t, b2, nullptr, h2, 512, 256, esrc, edst, E_SPLIT, N_EDGES, hist, bucket);

  // 6) norms (hist complete after GEMM2's fused dispatch)
  norms_kernel<<<(M_PAD + 255) / 256, 256, 0, stream>>>(hist, nsrc, ndst);

  // 7) MLP layer 3 -> u0 = bf16( nsrc * relu(h2@W3 + b3) )
  gemm_bt<128, 64, 64, 1, false><<<dim3(1, GY), 256, 0, stream>>>(
      h2, W3t, b3, nsrc, U0, 256, 64, nullptr, nullptr, 0, 0, nullptr, nullptr);

  // 8) fused GCN layers: agg(u) -> LDS hi/lo za -> MFMA(dup-W) -> u' (ping-pong U0/U1)
  gcn_layer<0><<<GY, 256, 0, stream>>>(U0, Wg1t, bucket, hist, ndst, nsrc, bg1, U1, nullptr);
  gcn_layer<0><<<GY, 256, 0, stream>>>(U1, Wg2t, bucket, hist, ndst, nsrc, bg2, U0, nullptr);
  gcn_layer<0><<<GY, 256, 0, stream>>>(U0, Wg3t, bucket, hist, ndst, nsrc, bg3, U1, nullptr);
  gcn_layer<1><<<GY, 256, 0, stream>>>(U1, Wg4t, bucket, hist, ndst, nsrc, bg4, nullptr, out);
}

// Round 4
// 818.476 us; speedup vs baseline: 1.3939x; 1.3939x over previous
//
#include <hip/hip_runtime.h>

#define N_NODES 100000
#define N_EDGES 1600000
#define M_PAD   100096   // 782 * 128
#define BCAP    64       // bucket capacity per node (Poisson(16): P(>=64) ~ 1e-20)
#define X_REAL 51200000L          // N_NODES*512
#define X_PAD  ((long)M_PAD*512)  // 51249152, divisible by 2048

typedef __bf16 bf16x8 __attribute__((ext_vector_type(8)));
typedef float  f32x4  __attribute__((ext_vector_type(4)));
typedef unsigned short u16x8 __attribute__((ext_vector_type(8)));

__device__ __forceinline__ unsigned short f2bf(float f) {
  union { float f; unsigned u; } x; x.f = f;
  unsigned r = (x.u + 0x7FFFu + ((x.u >> 16) & 1u)) >> 16;
  return (unsigned short)r;
}

__device__ __forceinline__ float bf2f(unsigned short h) {
  union { unsigned u; float f; } x; x.u = ((unsigned)h) << 16;
  return x.f;
}

__device__ __forceinline__ void async_copy16(const void* g, void* l) {
  __builtin_amdgcn_global_load_lds((__attribute__((address_space(1))) void*)g,
                                   (__attribute__((address_space(3))) void*)l,
                                   16, 0, 0);
}

// ---------------- prep kernels ----------------

__global__ void cvt_x_kernel(const float* __restrict__ x, unsigned short* __restrict__ xb) {
  long e = ((long)blockIdx.x * 256 + threadIdx.x) * 8;   // grid sized exactly: X_PAD/8/256 blocks
  u16x8 o;
  if (e < X_REAL) {
    float4 f0 = *(const float4*)(x + e);
    float4 f1 = *(const float4*)(x + e + 4);
    o[0] = f2bf(f0.x); o[1] = f2bf(f0.y); o[2] = f2bf(f0.z); o[3] = f2bf(f0.w);
    o[4] = f2bf(f1.x); o[5] = f2bf(f1.y); o[6] = f2bf(f1.z); o[7] = f2bf(f1.w);
  } else {
    o = (u16x8)0;
  }
  *(u16x8*)(xb + e) = o;
}

// W [K][N] fp32 -> Wt [Npad][K] bf16 (rows >= N zero-filled)
__global__ void cvt_wt_kernel(const float* __restrict__ W, unsigned short* __restrict__ Wt,
                              int K, int N, int Npad) {
  int idx = blockIdx.x * 256 + threadIdx.x;
  if (idx >= Npad * K) return;
  int n = idx / K, k = idx % K;
  Wt[idx] = (n < N) ? f2bf(W[(long)k * N + n]) : (unsigned short)0;
}

// W [64][N] fp32 -> Wt [64][128] bf16 with K duplicated: Wt[n][k] = W[k&63][n]
// (B operand for hi/lo-decomposed za: sum_k (hi_k + lo_k) * W)
__global__ void cvt_wt_dup_kernel(const float* __restrict__ W, unsigned short* __restrict__ Wt,
                                  int N) {
  int idx = blockIdx.x * 256 + threadIdx.x;
  if (idx >= 64 * 128) return;
  int n = idx >> 7, k = idx & 127;
  Wt[idx] = (n < N) ? f2bf(W[(long)(k & 63) * N + n]) : (unsigned short)0;
}

__global__ void norms_kernel(const int* __restrict__ hist,
                             float* __restrict__ nsrc, float* __restrict__ ndst) {
  int i = blockIdx.x * 256 + threadIdx.x;
  if (i >= M_PAD) return;
  if (i < N_NODES) {
    nsrc[i] = rsqrtf(fmaxf((float)hist[N_NODES + i], 1.f));  // deg_out
    ndst[i] = rsqrtf(fmaxf((float)hist[i], 1.f));            // deg_in
  } else {
    nsrc[i] = 1.f;
  }
}

// ---------------- GEMM: C = A(bf16,[M_PAD][K]) x Bt(bf16,[Nfull][K])^T ----------------
// EPI 0: bf16( relu(acc + bias[col]) )
// EPI 1: bf16( relu(acc + bias[col]) * rowscale[row] )
// EPI 4: f32 relu(acc + bias[col]) -> out[row][col], row<N_NODES, col<40 (final layer)
// EDGES: blocks with blockIdx.x == gridDim.x-1 build adjacency buckets + degree
//        histograms for ALL edges (atomic/scatter role overlapped with the GEMM;
//        interleaved in dispatch order -> co-resident with GEMM blocks).
template <int BM, int BN, int BK, int EPI, bool EDGES>
__launch_bounds__(256)
__global__ void gemm_bt(const unsigned short* __restrict__ A,
                        const unsigned short* __restrict__ Bt,
                        const float* __restrict__ bias,
                        const float* __restrict__ rowscale,
                        void* __restrict__ C, int K, int Nfull,
                        const int* __restrict__ esrc, const int* __restrict__ edst,
                        int* __restrict__ hist, int* __restrict__ bucket) {
  if constexpr (EDGES) {
    if (blockIdx.x == gridDim.x - 1) {
      const int stride = gridDim.y * 256;
      for (int e = blockIdx.y * 256 + threadIdx.x; e < N_EDGES; e += stride) {
        int s = esrc[e], d = edst[e];
        atomicAdd(&hist[N_NODES + s], 1);
        int p = atomicAdd(&hist[d], 1);
        if (p < BCAP) bucket[(size_t)d * BCAP + p] = s;
      }
      return;
    }
  }
  constexpr int WM = BM / 2, WN = BN / 2;
  constexpr int MI = WM / 16, NI = WN / 16;
  __shared__ __align__(16) unsigned short As[BM * BK];
  __shared__ __align__(16) unsigned short Bs[BN * BK];
  const int tid = threadIdx.x;
  const int wave = tid >> 6, lane = tid & 63;
  const int wm0 = (wave >> 1) * WM, wn0 = (wave & 1) * WN;
  const long rowBase = (long)blockIdx.y * BM;
  const int colBase = blockIdx.x * BN;
  const unsigned short* Ab = A + rowBase * K;
  const unsigned short* Bb = Bt + (long)colBase * K;
  f32x4 acc[MI][NI] = {};
  constexpr int ACH = BM * BK / 8;  // 16B chunks
  constexpr int BCH = BN * BK / 8;
  for (int k0 = 0; k0 < K; k0 += BK) {
#pragma unroll
    for (int c = tid; c < ACH; c += 256) {
      int r = (c * 8) / BK, cc = (c * 8) % BK;
      async_copy16(Ab + (long)r * K + k0 + cc, &As[c * 8]);
    }
#pragma unroll
    for (int c = tid; c < BCH; c += 256) {
      int r = (c * 8) / BK, cc = (c * 8) % BK;
      async_copy16(Bb + (long)r * K + k0 + cc, &Bs[c * 8]);
    }
    __syncthreads();
#pragma unroll
    for (int kk = 0; kk < BK; kk += 32) {
      bf16x8 af[MI], bfr[NI];
#pragma unroll
      for (int mi = 0; mi < MI; ++mi)
        af[mi] = *(const bf16x8*)&As[(wm0 + mi * 16 + (lane & 15)) * BK + kk + (lane >> 4) * 8];
#pragma unroll
      for (int ni = 0; ni < NI; ++ni)
        bfr[ni] = *(const bf16x8*)&Bs[(wn0 + ni * 16 + (lane & 15)) * BK + kk + (lane >> 4) * 8];
#pragma unroll
      for (int mi = 0; mi < MI; ++mi)
#pragma unroll
        for (int ni = 0; ni < NI; ++ni)
          acc[mi][ni] = __builtin_amdgcn_mfma_f32_16x16x32_bf16(af[mi], bfr[ni], acc[mi][ni], 0, 0, 0);
    }
    __syncthreads();
  }
  const int q = lane >> 4, c15 = lane & 15;
#pragma unroll
  for (int mi = 0; mi < MI; ++mi) {
#pragma unroll
    for (int ni = 0; ni < NI; ++ni) {
#pragma unroll
      for (int r = 0; r < 4; ++r) {
        long row = rowBase + wm0 + mi * 16 + q * 4 + r;
        int col = colBase + wn0 + ni * 16 + c15;
        float v = acc[mi][ni][r];
        if constexpr (EPI == 0) {
          v = fmaxf(v + bias[col], 0.f);
          ((unsigned short*)C)[row * Nfull + col] = f2bf(v);
        } else if constexpr (EPI == 1) {
          v = fmaxf(v + bias[col], 0.f) * rowscale[row];
          ((unsigned short*)C)[row * Nfull + col] = f2bf(v);
        } else {  // EPI == 4: final layer f32 out [N_NODES][40]
          float bv = (col < 40) ? bias[col] : 0.f;
          float vv = fmaxf(v + bv, 0.f);
          if (row < N_NODES && col < 40)
            ((float*)C)[row * 40 + col] = vv;
        }
      }
    }
  }
}

// ---------------- aggregation over bf16 u-rows (aggregate-first order) -------------
// za[node][0:64]  = bf16_hi( ndst[node] * sum_{s in bucket[node]} u[s][:] )
// za[node][64:128]= bf16_lo( residual )          (K=128 GEMM vs dup-W gives ~f32)
// One node per 64-lane wave (4 nodes/block, no LDS -> 8 blocks/CU, 32 waves/CU TLP).
// 8-way neighbor ILP: lane = slot*8 + colgrp; each lane covers 8 bf16 cols (16 B).
__global__ void agg_kernel(const unsigned short* __restrict__ u,
                           const int* __restrict__ bucket, const int* __restrict__ cnt,
                           const float* __restrict__ ndst,
                           unsigned short* __restrict__ za) {
  const int node = blockIdx.x * 4 + (threadIdx.x >> 6);
  const int lane = threadIdx.x & 63;
  const int r8 = lane >> 3;          // 0..7 neighbor slot
  const int c8 = (lane & 7) * 8;     // bf16 column start
  float a0 = 0.f, a1 = 0.f, a2 = 0.f, a3 = 0.f, a4 = 0.f, a5 = 0.f, a6 = 0.f, a7 = 0.f;
  int n = 0;
  if (node < N_NODES) n = min(cnt[node], BCAP);
  const int* bk = bucket + (size_t)node * BCAP;
#pragma unroll 2
  for (int i = r8; i < n; i += 8) {
    int s = bk[i];
    u16x8 v = *(const u16x8*)(u + (size_t)s * 64 + c8);
    a0 += bf2f(v[0]); a1 += bf2f(v[1]); a2 += bf2f(v[2]); a3 += bf2f(v[3]);
    a4 += bf2f(v[4]); a5 += bf2f(v[5]); a6 += bf2f(v[6]); a7 += bf2f(v[7]);
  }
#pragma unroll
  for (int m = 8; m <= 32; m <<= 1) {
    a0 += __shfl_xor(a0, m); a1 += __shfl_xor(a1, m);
    a2 += __shfl_xor(a2, m); a3 += __shfl_xor(a3, m);
    a4 += __shfl_xor(a4, m); a5 += __shfl_xor(a5, m);
    a6 += __shfl_xor(a6, m); a7 += __shfl_xor(a7, m);
  }
  if (r8 == 0) {
    float nd = (node < N_NODES) ? ndst[node] : 0.f;   // padded rows -> za = 0
    float vv[8] = {nd * a0, nd * a1, nd * a2, nd * a3, nd * a4, nd * a5, nd * a6, nd * a7};
    u16x8 H, L;
#pragma unroll
    for (int t = 0; t < 8; ++t) {
      unsigned short h = f2bf(vv[t]);
      H[t] = h;
      L[t] = f2bf(vv[t] - bf2f(h));
    }
    *(u16x8*)(za + (size_t)node * 128 + c8) = H;
    *(u16x8*)(za + (size_t)node * 128 + 64 + c8) = L;
  }
}

// ---------------- launch ----------------

extern "C" void kernel_launch(void* const* d_in, const int* in_sizes, int n_in,
                              void* d_out, int out_size, void* d_ws, size_t ws_size,
                              hipStream_t stream) {
  (void)in_sizes; (void)n_in; (void)out_size; (void)ws_size;
  const float* x   = (const float*)d_in[0];
  const int* esrc  = (const int*)d_in[1];
  const int* edst  = (const int*)d_in[2];
  const float* W1  = (const float*)d_in[3];  const float* b1  = (const float*)d_in[4];
  const float* W2  = (const float*)d_in[5];  const float* b2  = (const float*)d_in[6];
  const float* W3  = (const float*)d_in[7];  const float* b3  = (const float*)d_in[8];
  const float* Wg1 = (const float*)d_in[9];  const float* bg1 = (const float*)d_in[10];
  const float* Wg2 = (const float*)d_in[11]; const float* bg2 = (const float*)d_in[12];
  const float* Wg3 = (const float*)d_in[13]; const float* bg3 = (const float*)d_in[14];
  const float* Wg4 = (const float*)d_in[15]; const float* bg4 = (const float*)d_in[16];
  float* out = (float*)d_out;

  char* ws = (char*)d_ws;
  size_t off = 0;
  auto alloc = [&](size_t bytes) -> void* {
    void* p = ws + off;
    off += (bytes + 255) & ~(size_t)255;
    return p;
  };

  unsigned short* xb = (unsigned short*)alloc((size_t)M_PAD * 512 * 2);  // region0 (reused)
  unsigned short* h1 = (unsigned short*)alloc((size_t)M_PAD * 512 * 2);
  int*   bucket  = (int*)alloc((size_t)N_NODES * BCAP * 4);
  int*   hist    = (int*)alloc((size_t)2 * N_NODES * 4);
  float* nsrc    = (float*)alloc((size_t)M_PAD * 4);
  float* ndst    = (float*)alloc((size_t)N_NODES * 4);
  unsigned short* W1t  = (unsigned short*)alloc(512 * 512 * 2);
  unsigned short* W2t  = (unsigned short*)alloc(256 * 512 * 2);
  unsigned short* W3t  = (unsigned short*)alloc(64 * 256 * 2);
  unsigned short* Wg1t = (unsigned short*)alloc(64 * 128 * 2);   // dup-K layout
  unsigned short* Wg2t = (unsigned short*)alloc(64 * 128 * 2);
  unsigned short* Wg3t = (unsigned short*)alloc(64 * 128 * 2);
  unsigned short* Wg4t = (unsigned short*)alloc(64 * 128 * 2);

  // region0 reuse (xb dead after layer-1 GEMM); h2+U0+U1+za = M_PAD*512*2 B exactly:
  unsigned short* h2 = xb;                                                      // M_PAD*256 bf16
  unsigned short* U0 = (unsigned short*)((char*)xb + (size_t)M_PAD * 256 * 2);  // M_PAD*64 bf16
  unsigned short* U1 = (unsigned short*)((char*)U0 + (size_t)M_PAD * 64 * 2);   // M_PAD*64 bf16
  unsigned short* za = (unsigned short*)((char*)U1 + (size_t)M_PAD * 64 * 2);   // M_PAD*128 bf16

  // 1) zero both histograms — exact size
  hipMemsetAsync(hist, 0, (size_t)2 * N_NODES * 4, stream);

  // 2) x -> bf16 padded
  cvt_x_kernel<<<(int)(X_PAD / 8 / 256), 256, 0, stream>>>(x, xb);

  // 3) weights -> bf16 transposed [Npad][K]; GCN weights in dup-K [64][128]
  cvt_wt_kernel<<<(512 * 512 + 255) / 256, 256, 0, stream>>>(W1, W1t, 512, 512, 512);
  cvt_wt_kernel<<<(256 * 512 + 255) / 256, 256, 0, stream>>>(W2, W2t, 512, 256, 256);
  cvt_wt_kernel<<<(64 * 256 + 255) / 256, 256, 0, stream>>>(W3, W3t, 256, 64, 64);
  cvt_wt_dup_kernel<<<(64 * 128 + 255) / 256, 256, 0, stream>>>(Wg1, Wg1t, 64);
  cvt_wt_dup_kernel<<<(64 * 128 + 255) / 256, 256, 0, stream>>>(Wg2, Wg2t, 64);
  cvt_wt_dup_kernel<<<(64 * 128 + 255) / 256, 256, 0, stream>>>(Wg3, Wg3t, 64);
  cvt_wt_dup_kernel<<<(64 * 128 + 255) / 256, 256, 0, stream>>>(Wg4, Wg4t, 40);  // pad 40->64

  const int GY = M_PAD / 128;  // 782

  // 4) GEMM1 fused with edge-bucket build (ALL edges): x=0..3 GEMM cols, x=4 edge role.
  gemm_bt<128, 128, 64, 0, true><<<dim3(5, GY), 256, 0, stream>>>(
      xb, W1t, b1, nullptr, h1, 512, 512, esrc, edst, hist, bucket);

  // 5) norms (hist complete after fused dispatch)
  norms_kernel<<<(M_PAD + 255) / 256, 256, 0, stream>>>(hist, nsrc, ndst);

  // 6) rest of MLP
  gemm_bt<128, 128, 64, 0, false><<<dim3(2, GY), 256, 0, stream>>>(
      h1, W2t, b2, nullptr, h2, 512, 256, nullptr, nullptr, nullptr, nullptr);
  gemm_bt<128, 64, 64, 1, false><<<dim3(1, GY), 256, 0, stream>>>(
      h2, W3t, b3, nsrc, U0, 256, 64, nullptr, nullptr, nullptr, nullptr);

  // 7) GCN layers, aggregate-first: za = hi/lo(ndst * segsum(u)); u' = epilogue(za @ Wdup)
  agg_kernel<<<M_PAD / 4, 256, 0, stream>>>(U0, bucket, hist, ndst, za);
  gemm_bt<128, 64, 64, 1, false><<<dim3(1, GY), 256, 0, stream>>>(
      za, Wg1t, bg1, nsrc, U1, 128, 64, nullptr, nullptr, nullptr, nullptr);

  agg_kernel<<<M_PAD / 4, 256, 0, stream>>>(U1, bucket, hist, ndst, za);
  gemm_bt<128, 64, 64, 1, false><<<dim3(1, GY), 256, 0, stream>>>(
      za, Wg2t, bg2, nsrc, U0, 128, 64, nullptr, nullptr, nullptr, nullptr);

  agg_kernel<<<M_PAD / 4, 256, 0, stream>>>(U0, bucket, hist, ndst, za);
  gemm_bt<128, 64, 64, 1, false><<<dim3(1, GY), 256, 0, stream>>>(
      za, Wg3t, bg3, nsrc, U1, 128, 64, nullptr, nullptr, nullptr, nullptr);

  agg_kernel<<<M_PAD / 4, 256, 0, stream>>>(U1, bucket, hist, ndst, za);
  gemm_bt<128, 64, 64, 4, false><<<dim3(1, GY), 256, 0, stream>>>(
      za, Wg4t, bg4, nullptr, out, 128, 64, nullptr, nullptr, nullptr, nullptr);
}

// Round 5
// 788.666 us; speedup vs baseline: 1.4466x; 1.0378x over previous
//
#include <hip/hip_runtime.h>

#define N_NODES 100000
#define N_EDGES 1600000
#define M_PAD   100096   // 782 * 128
#define BCAP    64       // bucket capacity per node (Poisson(16): P(>=64) ~ 1e-20)
#define X_REAL 51200000L          // N_NODES*512
#define X_PAD  ((long)M_PAD*512)  // 51249152, divisible by 2048

typedef __bf16 bf16x8 __attribute__((ext_vector_type(8)));
typedef float  f32x4  __attribute__((ext_vector_type(4)));
typedef unsigned short u16x8 __attribute__((ext_vector_type(8)));

__device__ __forceinline__ unsigned short f2bf(float f) {
  union { float f; unsigned u; } x; x.f = f;
  unsigned r = (x.u + 0x7FFFu + ((x.u >> 16) & 1u)) >> 16;
  return (unsigned short)r;
}

__device__ __forceinline__ float bf2f(unsigned short h) {
  union { unsigned u; float f; } x; x.u = ((unsigned)h) << 16;
  return x.f;
}

__device__ __forceinline__ void async_copy16(const void* g, void* l) {
  __builtin_amdgcn_global_load_lds((__attribute__((address_space(1))) void*)g,
                                   (__attribute__((address_space(3))) void*)l,
                                   16, 0, 0);
}

// ---------------- prep kernels ----------------

__global__ void cvt_x_kernel(const float* __restrict__ x, unsigned short* __restrict__ xb) {
  long e = ((long)blockIdx.x * 256 + threadIdx.x) * 8;   // grid sized exactly: X_PAD/8/256 blocks
  u16x8 o;
  if (e < X_REAL) {
    float4 f0 = *(const float4*)(x + e);
    float4 f1 = *(const float4*)(x + e + 4);
    o[0] = f2bf(f0.x); o[1] = f2bf(f0.y); o[2] = f2bf(f0.z); o[3] = f2bf(f0.w);
    o[4] = f2bf(f1.x); o[5] = f2bf(f1.y); o[6] = f2bf(f1.z); o[7] = f2bf(f1.w);
  } else {
    o = (u16x8)0;
  }
  *(u16x8*)(xb + e) = o;
}

// W [K][N] fp32 -> Wt [Npad][K] bf16 (rows >= N zero-filled)
__global__ void cvt_wt_kernel(const float* __restrict__ W, unsigned short* __restrict__ Wt,
                              int K, int N, int Npad) {
  int idx = blockIdx.x * 256 + threadIdx.x;
  if (idx >= Npad * K) return;
  int n = idx / K, k = idx % K;
  Wt[idx] = (n < N) ? f2bf(W[(long)k * N + n]) : (unsigned short)0;
}

// W [64][N] fp32 -> Wt [64][128] bf16 with K duplicated: Wt[n][k] = W[k&63][n]
// (B operand for hi/lo-decomposed za: sum_k (hi_k + lo_k) * W)
__global__ void cvt_wt_dup_kernel(const float* __restrict__ W, unsigned short* __restrict__ Wt,
                                  int N) {
  int idx = blockIdx.x * 256 + threadIdx.x;
  if (idx >= 64 * 128) return;
  int n = idx >> 7, k = idx & 127;
  Wt[idx] = (n < N) ? f2bf(W[(long)(k & 63) * N + n]) : (unsigned short)0;
}

__global__ void norms_kernel(const int* __restrict__ hist,
                             float* __restrict__ nsrc, float* __restrict__ ndst) {
  int i = blockIdx.x * 256 + threadIdx.x;
  if (i >= M_PAD) return;
  if (i < N_NODES) {
    nsrc[i] = rsqrtf(fmaxf((float)hist[N_NODES + i], 1.f));  // deg_out
    ndst[i] = rsqrtf(fmaxf((float)hist[i], 1.f));            // deg_in
  } else {
    nsrc[i] = 1.f;
  }
}

// ---------------- GEMM: C = A(bf16,[M_PAD][K]) x Bt(bf16,[Nfull][K])^T ----------------
// EPI 0: bf16( relu(acc + bias[col]) )
// EPI 1: bf16( relu(acc + bias[col]) * rowscale[row] )
// EPI 4: f32 relu(acc + bias[col]) -> out[row][col], row<N_NODES, col<40 (final layer)
// EDGES: blocks with blockIdx.x == gridDim.x-1 build adjacency buckets + degree
//        histograms for ALL edges, 4-edge batched for atomic-latency ILP.
// TPB=512 uses 8 waves in a 2(M)x4(N) arrangement; TPB=256 uses 2x2.
template <int BM, int BN, int BK, int EPI, bool EDGES, int TPB>
__launch_bounds__(TPB)
__global__ void gemm_bt(const unsigned short* __restrict__ A,
                        const unsigned short* __restrict__ Bt,
                        const float* __restrict__ bias,
                        const float* __restrict__ rowscale,
                        void* __restrict__ C, int K, int Nfull,
                        const int* __restrict__ esrc, const int* __restrict__ edst,
                        int* __restrict__ hist, int* __restrict__ bucket) {
  if constexpr (EDGES) {
    if (blockIdx.x == gridDim.x - 1) {
      const int S = gridDim.y * TPB;
      int e = blockIdx.y * TPB + threadIdx.x;
      for (; e + 3 * S < N_EDGES; e += 4 * S) {
        int s0 = esrc[e],         d0 = edst[e];
        int s1 = esrc[e + S],     d1 = edst[e + S];
        int s2 = esrc[e + 2 * S], d2 = edst[e + 2 * S];
        int s3 = esrc[e + 3 * S], d3 = edst[e + 3 * S];
        atomicAdd(&hist[N_NODES + s0], 1);  // no-return atomics: fire-and-forget
        atomicAdd(&hist[N_NODES + s1], 1);
        atomicAdd(&hist[N_NODES + s2], 1);
        atomicAdd(&hist[N_NODES + s3], 1);
        int p0 = atomicAdd(&hist[d0], 1);   // 4 independent returning atomics in flight
        int p1 = atomicAdd(&hist[d1], 1);
        int p2 = atomicAdd(&hist[d2], 1);
        int p3 = atomicAdd(&hist[d3], 1);
        if (p0 < BCAP) bucket[(size_t)d0 * BCAP + p0] = s0;
        if (p1 < BCAP) bucket[(size_t)d1 * BCAP + p1] = s1;
        if (p2 < BCAP) bucket[(size_t)d2 * BCAP + p2] = s2;
        if (p3 < BCAP) bucket[(size_t)d3 * BCAP + p3] = s3;
      }
      for (; e < N_EDGES; e += S) {
        int s = esrc[e], d = edst[e];
        atomicAdd(&hist[N_NODES + s], 1);
        int p = atomicAdd(&hist[d], 1);
        if (p < BCAP) bucket[(size_t)d * BCAP + p] = s;
      }
      return;
    }
  }
  constexpr int WAVES = TPB / 64;
  constexpr int WAVES_M = 2, WAVES_N = WAVES / 2;  // 2x2 (TPB=256) or 2x4 (TPB=512)
  constexpr int WM = BM / WAVES_M, WN = BN / WAVES_N;
  constexpr int MI = WM / 16, NI = WN / 16;
  __shared__ __align__(16) unsigned short As[BM * BK];
  __shared__ __align__(16) unsigned short Bs[BN * BK];
  const int tid = threadIdx.x;
  const int wave = tid >> 6, lane = tid & 63;
  const int wm0 = (wave / WAVES_N) * WM, wn0 = (wave % WAVES_N) * WN;
  const long rowBase = (long)blockIdx.y * BM;
  const int colBase = blockIdx.x * BN;
  const unsigned short* Ab = A + rowBase * K;
  const unsigned short* Bb = Bt + (long)colBase * K;
  f32x4 acc[MI][NI] = {};
  constexpr int ACH = BM * BK / 8;  // 16B chunks
  constexpr int BCH = BN * BK / 8;
  for (int k0 = 0; k0 < K; k0 += BK) {
#pragma unroll
    for (int c = tid; c < ACH; c += TPB) {
      int r = (c * 8) / BK, cc = (c * 8) % BK;
      async_copy16(Ab + (long)r * K + k0 + cc, &As[c * 8]);
    }
#pragma unroll
    for (int c = tid; c < BCH; c += TPB) {
      int r = (c * 8) / BK, cc = (c * 8) % BK;
      async_copy16(Bb + (long)r * K + k0 + cc, &Bs[c * 8]);
    }
    __syncthreads();
#pragma unroll
    for (int kk = 0; kk < BK; kk += 32) {
      bf16x8 af[MI], bfr[NI];
#pragma unroll
      for (int mi = 0; mi < MI; ++mi)
        af[mi] = *(const bf16x8*)&As[(wm0 + mi * 16 + (lane & 15)) * BK + kk + (lane >> 4) * 8];
#pragma unroll
      for (int ni = 0; ni < NI; ++ni)
        bfr[ni] = *(const bf16x8*)&Bs[(wn0 + ni * 16 + (lane & 15)) * BK + kk + (lane >> 4) * 8];
#pragma unroll
      for (int mi = 0; mi < MI; ++mi)
#pragma unroll
        for (int ni = 0; ni < NI; ++ni)
          acc[mi][ni] = __builtin_amdgcn_mfma_f32_16x16x32_bf16(af[mi], bfr[ni], acc[mi][ni], 0, 0, 0);
    }
    __syncthreads();
  }
  const int q = lane >> 4, c15 = lane & 15;
#pragma unroll
  for (int mi = 0; mi < MI; ++mi) {
#pragma unroll
    for (int ni = 0; ni < NI; ++ni) {
#pragma unroll
      for (int r = 0; r < 4; ++r) {
        long row = rowBase + wm0 + mi * 16 + q * 4 + r;
        int col = colBase + wn0 + ni * 16 + c15;
        float v = acc[mi][ni][r];
        if constexpr (EPI == 0) {
          v = fmaxf(v + bias[col], 0.f);
          ((unsigned short*)C)[row * Nfull + col] = f2bf(v);
        } else if constexpr (EPI == 1) {
          v = fmaxf(v + bias[col], 0.f) * rowscale[row];
          ((unsigned short*)C)[row * Nfull + col] = f2bf(v);
        } else {  // EPI == 4: final layer f32 out [N_NODES][40]
          float bv = (col < 40) ? bias[col] : 0.f;
          float vv = fmaxf(v + bv, 0.f);
          if (row < N_NODES && col < 40)
            ((float*)C)[row * 40 + col] = vv;
        }
      }
    }
  }
}

// ---------------- aggregation over bf16 u-rows (aggregate-first order) -------------
// za[node][0:64]  = bf16_hi( ndst[node] * sum_{s in bucket[node]} u[s][:] )
// za[node][64:128]= bf16_lo( residual )          (K=128 GEMM vs dup-W gives ~f32)
// One node per 64-lane wave (4 nodes/block, no LDS -> high TLP).
// 8-way neighbor ILP: lane = slot*8 + colgrp; each lane covers 8 bf16 cols (16 B).
__global__ void agg_kernel(const unsigned short* __restrict__ u,
                           const int* __restrict__ bucket, const int* __restrict__ cnt,
                           const float* __restrict__ ndst,
                           unsigned short* __restrict__ za) {
  const int node = blockIdx.x * 4 + (threadIdx.x >> 6);
  const int lane = threadIdx.x & 63;
  const int r8 = lane >> 3;          // 0..7 neighbor slot
  const int c8 = (lane & 7) * 8;     // bf16 column start
  float a0 = 0.f, a1 = 0.f, a2 = 0.f, a3 = 0.f, a4 = 0.f, a5 = 0.f, a6 = 0.f, a7 = 0.f;
  int n = 0;
  if (node < N_NODES) n = min(cnt[node], BCAP);
  const int* bk = bucket + (size_t)node * BCAP;
#pragma unroll 2
  for (int i = r8; i < n; i += 8) {
    int s = bk[i];
    u16x8 v = *(const u16x8*)(u + (size_t)s * 64 + c8);
    a0 += bf2f(v[0]); a1 += bf2f(v[1]); a2 += bf2f(v[2]); a3 += bf2f(v[3]);
    a4 += bf2f(v[4]); a5 += bf2f(v[5]); a6 += bf2f(v[6]); a7 += bf2f(v[7]);
  }
#pragma unroll
  for (int m = 8; m <= 32; m <<= 1) {
    a0 += __shfl_xor(a0, m); a1 += __shfl_xor(a1, m);
    a2 += __shfl_xor(a2, m); a3 += __shfl_xor(a3, m);
    a4 += __shfl_xor(a4, m); a5 += __shfl_xor(a5, m);
    a6 += __shfl_xor(a6, m); a7 += __shfl_xor(a7, m);
  }
  if (r8 == 0) {
    float nd = (node < N_NODES) ? ndst[node] : 0.f;   // padded rows -> za = 0
    float vv[8] = {nd * a0, nd * a1, nd * a2, nd * a3, nd * a4, nd * a5, nd * a6, nd * a7};
    u16x8 H, L;
#pragma unroll
    for (int t = 0; t < 8; ++t) {
      unsigned short h = f2bf(vv[t]);
      H[t] = h;
      L[t] = f2bf(vv[t] - bf2f(h));
    }
    *(u16x8*)(za + (size_t)node * 128 + c8) = H;
    *(u16x8*)(za + (size_t)node * 128 + 64 + c8) = L;
  }
}

// ---------------- launch ----------------

extern "C" void kernel_launch(void* const* d_in, const int* in_sizes, int n_in,
                              void* d_out, int out_size, void* d_ws, size_t ws_size,
                              hipStream_t stream) {
  (void)in_sizes; (void)n_in; (void)out_size; (void)ws_size;
  const float* x   = (const float*)d_in[0];
  const int* esrc  = (const int*)d_in[1];
  const int* edst  = (const int*)d_in[2];
  const float* W1  = (const float*)d_in[3];  const float* b1  = (const float*)d_in[4];
  const float* W2  = (const float*)d_in[5];  const float* b2  = (const float*)d_in[6];
  const float* W3  = (const float*)d_in[7];  const float* b3  = (const float*)d_in[8];
  const float* Wg1 = (const float*)d_in[9];  const float* bg1 = (const float*)d_in[10];
  const float* Wg2 = (const float*)d_in[11]; const float* bg2 = (const float*)d_in[12];
  const float* Wg3 = (const float*)d_in[13]; const float* bg3 = (const float*)d_in[14];
  const float* Wg4 = (const float*)d_in[15]; const float* bg4 = (const float*)d_in[16];
  float* out = (float*)d_out;

  char* ws = (char*)d_ws;
  size_t off = 0;
  auto alloc = [&](size_t bytes) -> void* {
    void* p = ws + off;
    off += (bytes + 255) & ~(size_t)255;
    return p;
  };

  unsigned short* xb = (unsigned short*)alloc((size_t)M_PAD * 512 * 2);  // region0 (reused)
  unsigned short* h1 = (unsigned short*)alloc((size_t)M_PAD * 512 * 2);
  int*   bucket  = (int*)alloc((size_t)N_NODES * BCAP * 4);
  int*   hist    = (int*)alloc((size_t)2 * N_NODES * 4);
  float* nsrc    = (float*)alloc((size_t)M_PAD * 4);
  float* ndst    = (float*)alloc((size_t)N_NODES * 4);
  unsigned short* W1t  = (unsigned short*)alloc(512 * 512 * 2);
  unsigned short* W2t  = (unsigned short*)alloc(256 * 512 * 2);
  unsigned short* W3t  = (unsigned short*)alloc(64 * 256 * 2);
  unsigned short* Wg1t = (unsigned short*)alloc(64 * 128 * 2);   // dup-K layout
  unsigned short* Wg2t = (unsigned short*)alloc(64 * 128 * 2);
  unsigned short* Wg3t = (unsigned short*)alloc(64 * 128 * 2);
  unsigned short* Wg4t = (unsigned short*)alloc(64 * 128 * 2);

  // region0 reuse (xb dead after layer-1 GEMM); h2+U0+U1+za = M_PAD*512*2 B exactly:
  unsigned short* h2 = xb;                                                      // M_PAD*256 bf16
  unsigned short* U0 = (unsigned short*)((char*)xb + (size_t)M_PAD * 256 * 2);  // M_PAD*64 bf16
  unsigned short* U1 = (unsigned short*)((char*)U0 + (size_t)M_PAD * 64 * 2);   // M_PAD*64 bf16
  unsigned short* za = (unsigned short*)((char*)U1 + (size_t)M_PAD * 64 * 2);   // M_PAD*128 bf16

  // 1) zero both histograms — exact size
  hipMemsetAsync(hist, 0, (size_t)2 * N_NODES * 4, stream);

  // 2) x -> bf16 padded
  cvt_x_kernel<<<(int)(X_PAD / 8 / 256), 256, 0, stream>>>(x, xb);

  // 3) weights -> bf16 transposed [Npad][K]; GCN weights in dup-K [64][128]
  cvt_wt_kernel<<<(512 * 512 + 255) / 256, 256, 0, stream>>>(W1, W1t, 512, 512, 512);
  cvt_wt_kernel<<<(256 * 512 + 255) / 256, 256, 0, stream>>>(W2, W2t, 512, 256, 256);
  cvt_wt_kernel<<<(64 * 256 + 255) / 256, 256, 0, stream>>>(W3, W3t, 256, 64, 64);
  cvt_wt_dup_kernel<<<(64 * 128 + 255) / 256, 256, 0, stream>>>(Wg1, Wg1t, 64);
  cvt_wt_dup_kernel<<<(64 * 128 + 255) / 256, 256, 0, stream>>>(Wg2, Wg2t, 64);
  cvt_wt_dup_kernel<<<(64 * 128 + 255) / 256, 256, 0, stream>>>(Wg3, Wg3t, 64);
  cvt_wt_dup_kernel<<<(64 * 128 + 255) / 256, 256, 0, stream>>>(Wg4, Wg4t, 40);  // pad 40->64

  const int GY = M_PAD / 128;  // 782

  // 4) GEMM1 (BN=256, 512 threads) fused with edge-bucket build (ALL edges):
  //    x=0..1 GEMM cols, x=2 edge role. A logical reads halved vs BN=128.
  gemm_bt<128, 256, 64, 0, true, 512><<<dim3(3, GY), 512, 0, stream>>>(
      xb, W1t, b1, nullptr, h1, 512, 512, esrc, edst, hist, bucket);

  // 5) norms (hist complete after fused dispatch)
  norms_kernel<<<(M_PAD + 255) / 256, 256, 0, stream>>>(hist, nsrc, ndst);

  // 6) rest of MLP (GEMM2 BN=256: h1 read once)
  gemm_bt<128, 256, 64, 0, false, 512><<<dim3(1, GY), 512, 0, stream>>>(
      h1, W2t, b2, nullptr, h2, 512, 256, nullptr, nullptr, nullptr, nullptr);
  gemm_bt<128, 64, 64, 1, false, 256><<<dim3(1, GY), 256, 0, stream>>>(
      h2, W3t, b3, nsrc, U0, 256, 64, nullptr, nullptr, nullptr, nullptr);

  // 7) GCN layers, aggregate-first: za = hi/lo(ndst * segsum(u)); u' = epilogue(za @ Wdup)
  agg_kernel<<<M_PAD / 4, 256, 0, stream>>>(U0, bucket, hist, ndst, za);
  gemm_bt<128, 64, 64, 1, false, 256><<<dim3(1, GY), 256, 0, stream>>>(
      za, Wg1t, bg1, nsrc, U1, 128, 64, nullptr, nullptr, nullptr, nullptr);

  agg_kernel<<<M_PAD / 4, 256, 0, stream>>>(U1, bucket, hist, ndst, za);
  gemm_bt<128, 64, 64, 1, false, 256><<<dim3(1, GY), 256, 0, stream>>>(
      za, Wg2t, bg2, nsrc, U0, 128, 64, nullptr, nullptr, nullptr, nullptr);

  agg_kernel<<<M_PAD / 4, 256, 0, stream>>>(U0, bucket, hist, ndst, za);
  gemm_bt<128, 64, 64, 1, false, 256><<<dim3(1, GY), 256, 0, stream>>>(
      za, Wg3t, bg3, nsrc, U1, 128, 64, nullptr, nullptr, nullptr, nullptr);

  agg_kernel<<<M_PAD / 4, 256, 0, stream>>>(U1, bucket, hist, ndst, za);
  gemm_bt<128, 64, 64, 4, false, 256><<<dim3(1, GY), 256, 0, stream>>>(
      za, Wg4t, bg4, nullptr, out, 128, 64, nullptr, nullptr, nullptr, nullptr);
}